// Round 9
// baseline (552.706 us; speedup 1.0000x reference)
//
#include <hip/hip_runtime.h>
#include <hip/hip_bf16.h>

// B=128, N=50, NB=32, K=8, H=64, D=512. sites=6400, neighbor rows=204800.
// Fused: per block, 64 neighbor rows (=2 sites) GEMM (bf16 MFMA) into LDS zbuf
// (bf16), then 3 routing iterations in-block, write fp32 out.
// GEMM: BARRIER-FREE. No LDS staging — A and B fragments are loaded directly
// global->VGPR in MFMA fragment layout, register-double-buffered; the compiler
// inserts exact counted vmcnt waits (loads for step t+1 in flight while step t
// computes). Waves are fully independent until one __syncthreads before zbuf.

#define D_DIM 512
#define BM 64
#define KSTEPS 16

typedef __attribute__((ext_vector_type(8))) short short8;
typedef __attribute__((ext_vector_type(4))) short short4v;
typedef __attribute__((ext_vector_type(4))) float f32x4;

static __device__ __forceinline__ short f2bf(float f) {
    __bf16 b = (__bf16)f;
    return __builtin_bit_cast(short, b);
}
static __device__ __forceinline__ float bf2f(short s) {
    unsigned u = ((unsigned)(unsigned short)s) << 16;
    return __builtin_bit_cast(float, u);
}

__global__ __launch_bounds__(256) void wconv(const float* __restrict__ W,
                                             short* __restrict__ Wb) {
    const int i = (blockIdx.x * 256 + threadIdx.x) * 8;
    const float4 v0 = *reinterpret_cast<const float4*>(W + i);
    const float4 v1 = *reinterpret_cast<const float4*>(W + i + 4);
    short8 o;
    o[0] = f2bf(v0.x); o[1] = f2bf(v0.y); o[2] = f2bf(v0.z); o[3] = f2bf(v0.w);
    o[4] = f2bf(v1.x); o[5] = f2bf(v1.y); o[6] = f2bf(v1.z); o[7] = f2bf(v1.w);
    *reinterpret_cast<short8*>(Wb + i) = o;
}

// 256 threads = 4 waves; wave w -> all 64 rows x cols [128w,128w+128).
// A-frag m (16 rows x 32 k fp32): lane l reads row m*16+(l&15), k-off (l>>4)*8.
// B-frag n (16 cols x 32 k bf16): lane l reads Wb row wc+n*16+(l&15), same k.
template <bool FUSED>
__global__ __launch_bounds__(256, 2) void gemm_route(
    const float* __restrict__ A,     // [R,512] fp32
    const short* __restrict__ Wb,    // [512,512] bf16
    const float* __restrict__ bias,  // [512]
    short* __restrict__ Zs,          // !FUSED: s output bf16
    const short* __restrict__ S,     // FUSED: s input bf16
    const int* __restrict__ miter_ptr,
    float* __restrict__ out)         // FUSED: [sites,512] fp32
{
    __shared__ __align__(16) char smem[71680];   // zbuf 64K + u 4K + p 2K

    const int t = threadIdx.x;
    const int lane = t & 63;
    const int wid = t >> 6;
    const size_t row0 = (size_t)blockIdx.x * BM;
    const int wc = wid * 128;

    const int cb = wc + (lane & 15);
    float bcol[8];
    #pragma unroll
    for (int n = 0; n < 8; ++n) bcol[n] = bias[cb + n * 16];
    int miter = 0;
    if (FUSED) miter = *miter_ptr;

    // per-lane fragment base pointers
    const float* const aBase = A + (row0 + (lane & 15)) * D_DIM + (lane >> 4) * 8;
    const short* const bBase = Wb + (size_t)(wc + (lane & 15)) * D_DIM + (lane >> 4) * 8;

    float4 aR[2][8];   // [buf][2m, 2m+1] fp32 halves of A-frag m
    short8 bR[2][8];   // [buf][n] B-frags

    auto loadStep = [&](int k0, int buf) {
        #pragma unroll
        for (int m = 0; m < 4; ++m) {
            const float* p = aBase + m * 16 * D_DIM + k0;
            aR[buf][2 * m]     = *reinterpret_cast<const float4*>(p);
            aR[buf][2 * m + 1] = *reinterpret_cast<const float4*>(p + 4);
        }
        #pragma unroll
        for (int n = 0; n < 8; ++n)
            bR[buf][n] = *reinterpret_cast<const short8*>(bBase + n * 16 * D_DIM + k0);
    };

    f32x4 acc[4][8] = {};

    loadStep(0, 0);
    #pragma unroll
    for (int tk = 0; tk < KSTEPS; ++tk) {
        const int cur = tk & 1;
        // convert cur A frags first (kills aR[cur] early, freeing pressure)
        short8 af[4];
        #pragma unroll
        for (int m = 0; m < 4; ++m) {
            short8 f;
            #pragma unroll
            for (int j = 0; j < 4; ++j) {
                f[j]     = f2bf(aR[cur][2 * m][j]);
                f[4 + j] = f2bf(aR[cur][2 * m + 1][j]);
            }
            af[m] = f;
        }
        if (tk < KSTEPS - 1) loadStep((tk + 1) * 32, cur ^ 1);  // in flight across compute
        #pragma unroll
        for (int m = 0; m < 4; ++m)
            #pragma unroll
            for (int n = 0; n < 8; ++n)
                acc[m][n] = __builtin_amdgcn_mfma_f32_16x16x32_bf16(
                    af[m], bR[cur][n], acc[m][n], 0, 0, 0);
    }

    // ---- epilogue: bias + ReLU + l2norm per 64-col group; z as bf16.
    short* const zbuf = (short*)smem;            // [64][512] bf16
    #pragma unroll
    for (int m = 0; m < 4; ++m) {
        #pragma unroll
        for (int r = 0; r < 4; ++r) {
            float v[8];
            float ssa = 0.0f, ssb = 0.0f;
            #pragma unroll
            for (int n = 0; n < 4; ++n) {
                v[n] = fmaxf(acc[m][n][r] + bcol[n], 0.0f);
                ssa = fmaf(v[n], v[n], ssa);
            }
            #pragma unroll
            for (int n = 4; n < 8; ++n) {
                v[n] = fmaxf(acc[m][n][r] + bcol[n], 0.0f);
                ssb = fmaf(v[n], v[n], ssb);
            }
            ssa += __shfl_xor(ssa, 1); ssb += __shfl_xor(ssb, 1);
            ssa += __shfl_xor(ssa, 2); ssb += __shfl_xor(ssb, 2);
            ssa += __shfl_xor(ssa, 4); ssb += __shfl_xor(ssb, 4);
            ssa += __shfl_xor(ssa, 8); ssb += __shfl_xor(ssb, 8);
            const float inva = 1.0f / fmaxf(sqrtf(ssa), 1e-12f);
            const float invb = 1.0f / fmaxf(sqrtf(ssb), 1e-12f);
            const int orow = m * 16 + (lane >> 4) * 4 + r;   // 0..63
            if (FUSED) {
                #pragma unroll
                for (int n = 0; n < 4; ++n)
                    zbuf[orow * D_DIM + cb + n * 16] = f2bf(v[n] * inva);
                #pragma unroll
                for (int n = 4; n < 8; ++n)
                    zbuf[orow * D_DIM + cb + n * 16] = f2bf(v[n] * invb);
            } else {
                #pragma unroll
                for (int n = 0; n < 4; ++n)
                    Zs[(row0 + orow) * D_DIM + cb + n * 16] = f2bf(v[n] * inva);
                #pragma unroll
                for (int n = 4; n < 8; ++n)
                    Zs[(row0 + orow) * D_DIM + cb + n * 16] = f2bf(v[n] * invb);
            }
        }
    }

    if (!FUSED) return;
    __syncthreads();   // zbuf complete (the only block-wide barrier)

    // ---- routing (verified): 2 sites/block, 128 threads each; 4 elems/thread.
    const int tt = t & 127;
    const int ssid = t >> 7;
    const size_t site = (size_t)blockIdx.x * 2 + ssid;
    float* const u_ = (float*)(smem + 65536) + ssid * 512;
    float* const p_ = (float*)(smem + 69632) + ssid * 256;
    const short* const zr = zbuf + ssid * 32 * D_DIM;

    const int e = tt * 4;
    const int go = tt >> 4;                  // capsule group of owned elems
    const short4v sv = *reinterpret_cast<const short4v*>(S + site * D_DIM + e);
    const float s0 = bf2f(sv[0]), s1 = bf2f(sv[1]);
    const float s2 = bf2f(sv[2]), s3 = bf2f(sv[3]);

    float v0, v1, v2, v3;
    {   // iteration 0: p uniform 1/8
        float a0 = 0, a1 = 0, a2 = 0, a3 = 0;
        for (int m = 0; m < 32; ++m) {
            const short4v z = *reinterpret_cast<const short4v*>(zr + m * D_DIM + e);
            a0 += bf2f(z[0]); a1 += bf2f(z[1]); a2 += bf2f(z[2]); a3 += bf2f(z[3]);
        }
        v0 = fmaf(a0, 0.125f, s0); v1 = fmaf(a1, 0.125f, s1);
        v2 = fmaf(a2, 0.125f, s2); v3 = fmaf(a3, 0.125f, s3);
    }

    const int dm = tt >> 2;                  // neighbor for this thread's dots
    const int ka = (tt & 3) * 2;             // capsule pair

    for (int it = 1; it < miter; ++it) {
        float ssum = v0 * v0 + v1 * v1 + v2 * v2 + v3 * v3;
        ssum += __shfl_xor(ssum, 1);
        ssum += __shfl_xor(ssum, 2);
        ssum += __shfl_xor(ssum, 4);
        ssum += __shfl_xor(ssum, 8);
        const float inv = 1.0f / fmaxf(sqrtf(ssum), 1e-12f);
        v0 *= inv; v1 *= inv; v2 *= inv; v3 *= inv;
        *reinterpret_cast<float4*>(u_ + e) = make_float4(v0, v1, v2, v3);
        __syncthreads();

        // dots: p[dm][ka], p[dm][ka+1]; staggered octet reads
        const short* const za = zr + dm * D_DIM + ka * 64;
        const float* const ua = u_ + ka * 64;
        float da = 0, db = 0;
        #pragma unroll
        for (int j = 0; j < 8; ++j) {
            const int jj = ((j + (tt & 7)) & 7) * 8;
            const short8 zva = *reinterpret_cast<const short8*>(za + jj);
            const short8 zvb = *reinterpret_cast<const short8*>(za + 64 + jj);
            const f32x4 uA0 = *reinterpret_cast<const f32x4*>(ua + jj);
            const f32x4 uA1 = *reinterpret_cast<const f32x4*>(ua + jj + 4);
            const f32x4 uB0 = *reinterpret_cast<const f32x4*>(ua + 64 + jj);
            const f32x4 uB1 = *reinterpret_cast<const f32x4*>(ua + 64 + jj + 4);
            #pragma unroll
            for (int qq = 0; qq < 4; ++qq) {
                da = fmaf(bf2f(zva[qq]), uA0[qq], da);
                da = fmaf(bf2f(zva[qq + 4]), uA1[qq], da);
                db = fmaf(bf2f(zvb[qq]), uB0[qq], db);
                db = fmaf(bf2f(zvb[qq + 4]), uB1[qq], db);
            }
        }
        // softmax over 8 k (4 threads x 2 vals)
        float mx = fmaxf(da, db);
        mx = fmaxf(mx, __shfl_xor(mx, 1));
        mx = fmaxf(mx, __shfl_xor(mx, 2));
        const float ea = __expf(da - mx), eb = __expf(db - mx);
        float sm_ = ea + eb;
        sm_ += __shfl_xor(sm_, 1);
        sm_ += __shfl_xor(sm_, 2);
        const float rs = 1.0f / sm_;
        *reinterpret_cast<float2*>(p_ + dm * 8 + ka) = make_float2(ea * rs, eb * rs);
        __syncthreads();

        // u = s + sum_m z[m]*p[m, go]
        float a0 = 0, a1 = 0, a2 = 0, a3 = 0;
        for (int m = 0; m < 32; ++m) {
            const short4v z = *reinterpret_cast<const short4v*>(zr + m * D_DIM + e);
            const float pm = p_[m * 8 + go];
            a0 = fmaf(bf2f(z[0]), pm, a0); a1 = fmaf(bf2f(z[1]), pm, a1);
            a2 = fmaf(bf2f(z[2]), pm, a2); a3 = fmaf(bf2f(z[3]), pm, a3);
        }
        v0 = s0 + a0; v1 = s1 + a1; v2 = s2 + a2; v3 = s3 + a3;
    }

    *reinterpret_cast<float4*>(out + site * D_DIM + e) =
        make_float4(fmaxf(v0, 0.0f), fmaxf(v1, 0.0f),
                    fmaxf(v2, 0.0f), fmaxf(v3, 0.0f));
}

extern "C" void kernel_launch(void* const* d_in, const int* in_sizes, int n_in,
                              void* d_out, int out_size, void* d_ws, size_t ws_size,
                              hipStream_t stream) {
    const float* self_v  = (const float*)d_in[0];   // [6400,512]
    const float* neigh_v = (const float*)d_in[1];   // [204800,512]
    const float* W1      = (const float*)d_in[2];   // [512,512]
    const float* b1      = (const float*)d_in[3];   // [512]
    const int*   miter   = (const int*)d_in[4];
    float* out = (float*)d_out;

    const int sites = in_sizes[0] / D_DIM;          // 6400
    const int nrows = in_sizes[1] / D_DIM;          // 204800

    short* s  = (short*)d_ws;                       // [sites,512] bf16
    short* Wb = s + (size_t)sites * D_DIM;          // [512,512] bf16

    wconv<<<dim3(D_DIM * D_DIM / (256 * 8)), dim3(256), 0, stream>>>(W1, Wb);
    gemm_route<false><<<dim3(sites / BM), dim3(256), 0, stream>>>(
        self_v, Wb, b1, s, nullptr, nullptr, nullptr);
    gemm_route<true><<<dim3(nrows / BM), dim3(256), 0, stream>>>(
        neigh_v, Wb, b1, nullptr, s, miter, out);
}

// Round 10
// 457.660 us; speedup vs baseline: 1.2077x; 1.2077x over previous
//
#include <hip/hip_runtime.h>
#include <hip/hip_bf16.h>

// B=128, N=50, NB=32, K=8, H=64, D=512. sites=6400, neighbor rows=204800.
// Fused: per block, 64 neighbor rows (=2 sites) GEMM (bf16 MFMA, round-8
// verified DMA pipeline) -> z stays IN THE ACCUMULATOR REGISTERS (f32).
// Routing runs register-space: dots via 16-lane shfl reduce, column sums via
// q-lane (xor 16/32) shfl reduce, softmax through a 2 KB LDS p-buffer.
// No zbuf, no routing LDS traffic.

#define D_DIM 512
#define BM 64
#define BK 32
#define KSTEPS 16

typedef __attribute__((ext_vector_type(8))) short short8;
typedef __attribute__((ext_vector_type(4))) float f32x4;

static __device__ __forceinline__ short f2bf(float f) {
    __bf16 b = (__bf16)f;
    return __builtin_bit_cast(short, b);
}
static __device__ __forceinline__ float bf2f(short s) {
    unsigned u = ((unsigned)(unsigned short)s) << 16;
    return __builtin_bit_cast(float, u);
}
static __device__ __forceinline__ void gload_lds16(const void* g, void* l) {
    __builtin_amdgcn_global_load_lds(
        (const __attribute__((address_space(1))) void*)g,
        (__attribute__((address_space(3))) void*)l, 16, 0, 0);
}

__global__ __launch_bounds__(256) void wconv(const float* __restrict__ W,
                                             short* __restrict__ Wb) {
    const int i = (blockIdx.x * 256 + threadIdx.x) * 8;
    const float4 v0 = *reinterpret_cast<const float4*>(W + i);
    const float4 v1 = *reinterpret_cast<const float4*>(W + i + 4);
    short8 o;
    o[0] = f2bf(v0.x); o[1] = f2bf(v0.y); o[2] = f2bf(v0.z); o[3] = f2bf(v0.w);
    o[4] = f2bf(v1.x); o[5] = f2bf(v1.y); o[6] = f2bf(v1.z); o[7] = f2bf(v1.w);
    *reinterpret_cast<short8*>(Wb + i) = o;
}

// 256 threads = 4 waves; wave w -> 64 rows x cols [128w,128w+128).
// acc[mi][n][r]: row = mi*16 + q*4 + r (q = lane>>4), col = wc + n*16 + (lane&15).
// Site of a row = row>>5 (mi 0,1 -> site0; mi 2,3 -> site1).
template <bool FUSED>
__global__ __launch_bounds__(256, 2) void gemm_route(
    const float* __restrict__ A,     // [R,512] fp32
    const short* __restrict__ Wb,    // [512,512] bf16
    const float* __restrict__ bias,  // [512]
    short* __restrict__ Zs,          // !FUSED: s output bf16
    const short* __restrict__ S,     // FUSED: s input bf16
    const int* __restrict__ miter_ptr,
    float* __restrict__ out)         // FUSED: [sites,512] fp32
{
    __shared__ __align__(16) char smem[81920];
    float* const lAf32 = (float*)smem;           // [2][2048] f32  (16 KB)
    short* const lB = (short*)(smem + 16384);    // [2][16384] bf16 (64 KB)

    const int t = threadIdx.x;
    const int lane = t & 63;
    const int wid = t >> 6;
    const size_t row0 = (size_t)blockIdx.x * BM;
    const int wc = wid * 128;
    const int l15 = lane & 15;
    const int q = lane >> 4;

    const int cb = wc + l15;
    float bcol[8];
    #pragma unroll
    for (int n = 0; n < 8; ++n) bcol[n] = bias[cb + n * 16];
    int miter = 0;
    if (FUSED) miter = *miter_ptr;

    // 10 DMAs per wave per step: 8 B-chunks + 2 A-chunks (1024 B each).
    auto stage = [&](int step, int buf) {
        const int k0 = (step < KSTEPS ? step : 0) * BK;
        #pragma unroll
        for (int i = 0; i < 8; ++i) {            // B: chunk = 16 rows x 64 B
            const int c = wid * 8 + i;
            const int r = c * 16 + (lane >> 2);
            const int g = ((lane & 3) - (r >> 1)) & 3;
            gload_lds16(Wb + (size_t)r * D_DIM + k0 + g * 8,
                        lB + buf * 16384 + c * 512);
        }
        #pragma unroll
        for (int i = 0; i < 2; ++i) {            // A: chunk = 8 rows x 128 B
            const int c = wid * 2 + i;
            const int r = c * 8 + (lane >> 3);
            const int g = ((lane & 7) - 2 * (r & 3)) & 7;
            gload_lds16(A + (row0 + r) * D_DIM + k0 + g * 4,
                        lAf32 + buf * 2048 + c * 256);
        }
    };

    f32x4 acc[4][8] = {};
    auto compute = [&](int buf) {
        const int sq = lane >> 4;                // k 16B-slot pair index
        short8 af[4], bfr[8];
        #pragma unroll
        for (int m = 0; m < 4; ++m) {
            const int r = m * 16 + l15;
            const float* ap = lAf32 + buf * 2048 + r * 32 + ((sq + (r & 3)) & 3) * 8;
            const f32x4 a0 = *reinterpret_cast<const f32x4*>(ap);
            const f32x4 a1 = *reinterpret_cast<const f32x4*>(ap + 4);
            short8 f;
            f[0] = f2bf(a0[0]); f[1] = f2bf(a0[1]);
            f[2] = f2bf(a0[2]); f[3] = f2bf(a0[3]);
            f[4] = f2bf(a1[0]); f[5] = f2bf(a1[1]);
            f[6] = f2bf(a1[2]); f[7] = f2bf(a1[3]);
            af[m] = f;
        }
        #pragma unroll
        for (int n = 0; n < 8; ++n) {
            const int r = wc + n * 16 + l15;
            bfr[n] = *reinterpret_cast<const short8*>(
                lB + buf * 16384 + r * 32 + ((sq + (r >> 1)) & 3) * 8);
        }
        __builtin_amdgcn_s_setprio(1);
        #pragma unroll
        for (int m = 0; m < 4; ++m)
            #pragma unroll
            for (int n = 0; n < 8; ++n)
                acc[m][n] = __builtin_amdgcn_mfma_f32_16x16x32_bf16(
                    af[m], bfr[n], acc[m][n], 0, 0, 0);
        __builtin_amdgcn_s_setprio(0);
    };

    // ---- pipeline (round-8 verified): counted vmcnt, single op type
    stage(0, 0);
    stage(1, 1);
    asm volatile("s_waitcnt vmcnt(10)" ::: "memory");
    __builtin_amdgcn_s_barrier();
    #pragma unroll
    for (int tk = 0; tk < KSTEPS; ++tk) {
        compute(tk & 1);
        asm volatile("s_waitcnt lgkmcnt(0)" ::: "memory");
        __builtin_amdgcn_s_barrier();
        stage(tk + 2, tk & 1);
        asm volatile("s_waitcnt vmcnt(10)" ::: "memory");
        __builtin_amdgcn_s_barrier();
    }
    asm volatile("s_waitcnt vmcnt(0)" ::: "memory");
    __builtin_amdgcn_s_barrier();

    // ---- epilogue: bias + ReLU + l2norm per 64-col group; z kept in acc (f32).
    #pragma unroll
    for (int m = 0; m < 4; ++m) {
        #pragma unroll
        for (int r = 0; r < 4; ++r) {
            float v[8];
            float ssa = 0.0f, ssb = 0.0f;
            #pragma unroll
            for (int n = 0; n < 4; ++n) {
                v[n] = fmaxf(acc[m][n][r] + bcol[n], 0.0f);
                ssa = fmaf(v[n], v[n], ssa);
            }
            #pragma unroll
            for (int n = 4; n < 8; ++n) {
                v[n] = fmaxf(acc[m][n][r] + bcol[n], 0.0f);
                ssb = fmaf(v[n], v[n], ssb);
            }
            ssa += __shfl_xor(ssa, 1); ssb += __shfl_xor(ssb, 1);
            ssa += __shfl_xor(ssa, 2); ssb += __shfl_xor(ssb, 2);
            ssa += __shfl_xor(ssa, 4); ssb += __shfl_xor(ssb, 4);
            ssa += __shfl_xor(ssa, 8); ssb += __shfl_xor(ssb, 8);
            const float inva = 1.0f / fmaxf(sqrtf(ssa), 1e-12f);
            const float invb = 1.0f / fmaxf(sqrtf(ssb), 1e-12f);
            if (FUSED) {
                #pragma unroll
                for (int n = 0; n < 4; ++n) acc[m][n][r] = v[n] * inva;
                #pragma unroll
                for (int n = 4; n < 8; ++n) acc[m][n][r] = v[n] * invb;
            } else {
                const int orow = m * 16 + q * 4 + r;
                #pragma unroll
                for (int n = 0; n < 4; ++n)
                    Zs[(row0 + orow) * D_DIM + cb + n * 16] = f2bf(v[n] * inva);
                #pragma unroll
                for (int n = 4; n < 8; ++n)
                    Zs[(row0 + orow) * D_DIM + cb + n * 16] = f2bf(v[n] * invb);
            }
        }
    }

    if (!FUSED) return;

    // ---- register-space routing. praw[2 sites][32 m][8 k] f32 = 2 KB.
    float* const praw = (float*)smem;            // aliases lAf32 (drained above)
    const size_t site0 = (size_t)blockIdx.x * 2;

    // s input: per lane, both sites, its 8 columns
    float sreg[2][8];
    #pragma unroll
    for (int st = 0; st < 2; ++st)
        #pragma unroll
        for (int n = 0; n < 8; ++n)
            sreg[st][n] = bf2f(S[(site0 + st) * D_DIM + cb + n * 16]);

    float u[2][8];
    // iteration 0: p uniform 1/8 -> u = s + 0.125 * colsum(z)
    #pragma unroll
    for (int st = 0; st < 2; ++st)
        #pragma unroll
        for (int n = 0; n < 8; ++n) {
            float c = 0.0f;
            #pragma unroll
            for (int mi = 2 * st; mi < 2 * st + 2; ++mi)
                #pragma unroll
                for (int r = 0; r < 4; ++r) c += acc[mi][n][r];
            c += __shfl_xor(c, 16);
            c += __shfl_xor(c, 32);
            u[st][n] = fmaf(c, 0.125f, sreg[st][n]);
        }

    for (int it = 1; it < miter; ++it) {
        // l2norm u per (site, group): group g = n-quad; reduce over l15
        #pragma unroll
        for (int st = 0; st < 2; ++st)
            #pragma unroll
            for (int g = 0; g < 2; ++g) {
                float ss = 0.0f;
                #pragma unroll
                for (int n = 4 * g; n < 4 * g + 4; ++n)
                    ss = fmaf(u[st][n], u[st][n], ss);
                ss += __shfl_xor(ss, 1);
                ss += __shfl_xor(ss, 2);
                ss += __shfl_xor(ss, 4);
                ss += __shfl_xor(ss, 8);
                const float inv = 1.0f / fmaxf(sqrtf(ss), 1e-12f);
                #pragma unroll
                for (int n = 4 * g; n < 4 * g + 4; ++n) u[st][n] *= inv;
            }

        // dots: d[g] = z_row . u_group, reduced over l15; lane keeps its own
        float pd0 = 0.0f, pd1 = 0.0f;
        #pragma unroll
        for (int mi = 0; mi < 4; ++mi)
            #pragma unroll
            for (int r = 0; r < 4; ++r) {
                const int st = mi >> 1;
                float d0 = 0.0f, d1 = 0.0f;
                #pragma unroll
                for (int n = 0; n < 4; ++n) {
                    d0 = fmaf(acc[mi][n][r], u[st][n], d0);
                    d1 = fmaf(acc[mi][n + 4][r], u[st][n + 4], d1);
                }
                d0 += __shfl_xor(d0, 1); d1 += __shfl_xor(d1, 1);
                d0 += __shfl_xor(d0, 2); d1 += __shfl_xor(d1, 2);
                d0 += __shfl_xor(d0, 4); d1 += __shfl_xor(d1, 4);
                d0 += __shfl_xor(d0, 8); d1 += __shfl_xor(d1, 8);
                if (l15 == mi * 4 + r) { pd0 = d0; pd1 = d1; }
            }
        // lane's own (site, m): site_w = l15>>3, m_w = ((l15>>2)&1)*16 + q*4 + (l15&3)
        {
            const int site_w = l15 >> 3;
            const int m_w = ((l15 >> 2) & 1) * 16 + q * 4 + (l15 & 3);
            praw[(site_w * 32 + m_w) * 8 + 2 * wid]     = pd0;
            praw[(site_w * 32 + m_w) * 8 + 2 * wid + 1] = pd1;
        }
        __syncthreads();

        // softmax over k for each (site, m): 64 threads
        if (t < 64) {
            float* pr = praw + t * 8;
            float mx = pr[0];
            #pragma unroll
            for (int k = 1; k < 8; ++k) mx = fmaxf(mx, pr[k]);
            float sum = 0.0f;
            float e[8];
            #pragma unroll
            for (int k = 0; k < 8; ++k) { e[k] = __expf(pr[k] - mx); sum += e[k]; }
            const float rs = 1.0f / sum;
            #pragma unroll
            for (int k = 0; k < 8; ++k) pr[k] = e[k] * rs;
        }
        __syncthreads();

        // u = s + sum_m p[m,k] * z[m]; partial per lane, reduce over q
        float cacc[2][8] = {};
        #pragma unroll
        for (int mi = 0; mi < 4; ++mi)
            #pragma unroll
            for (int r = 0; r < 4; ++r) {
                const int st = mi >> 1;
                const int m_w = (mi & 1) * 16 + q * 4 + r;
                const float p0 = praw[(st * 32 + m_w) * 8 + 2 * wid];
                const float p1 = praw[(st * 32 + m_w) * 8 + 2 * wid + 1];
                #pragma unroll
                for (int n = 0; n < 4; ++n) {
                    cacc[st][n]     = fmaf(acc[mi][n][r],     p0, cacc[st][n]);
                    cacc[st][n + 4] = fmaf(acc[mi][n + 4][r], p1, cacc[st][n + 4]);
                }
            }
        #pragma unroll
        for (int st = 0; st < 2; ++st)
            #pragma unroll
            for (int n = 0; n < 8; ++n) {
                float c = cacc[st][n];
                c += __shfl_xor(c, 16);
                c += __shfl_xor(c, 32);
                u[st][n] = sreg[st][n] + c;
            }
        __syncthreads();   // praw reads done before next iteration's writes
    }

    // output: q0->site0 n0-3, q1->site1 n0-3, q2->site0 n4-7, q3->site1 n4-7
    {
        const int st = q & 1;
        const int nb = (q >> 1) * 4;
        #pragma unroll
        for (int j = 0; j < 4; ++j) {
            const int n = nb + j;
            out[(site0 + st) * D_DIM + cb + n * 16] = fmaxf(u[st][n], 0.0f);
        }
    }
}

extern "C" void kernel_launch(void* const* d_in, const int* in_sizes, int n_in,
                              void* d_out, int out_size, void* d_ws, size_t ws_size,
                              hipStream_t stream) {
    const float* self_v  = (const float*)d_in[0];   // [6400,512]
    const float* neigh_v = (const float*)d_in[1];   // [204800,512]
    const float* W1      = (const float*)d_in[2];   // [512,512]
    const float* b1      = (const float*)d_in[3];   // [512]
    const int*   miter   = (const int*)d_in[4];
    float* out = (float*)d_out;

    const int sites = in_sizes[0] / D_DIM;          // 6400
    const int nrows = in_sizes[1] / D_DIM;          // 204800

    short* s  = (short*)d_ws;                       // [sites,512] bf16
    short* Wb = s + (size_t)sites * D_DIM;          // [512,512] bf16

    wconv<<<dim3(D_DIM * D_DIM / (256 * 8)), dim3(256), 0, stream>>>(W1, Wb);
    gemm_route<false><<<dim3(sites / BM), dim3(256), 0, stream>>>(
        self_v, Wb, b1, s, nullptr, nullptr, nullptr);
    gemm_route<true><<<dim3(nrows / BM), dim3(256), 0, stream>>>(
        neigh_v, Wb, b1, nullptr, s, miter, out);
}

// Round 11
// 251.526 us; speedup vs baseline: 2.1974x; 1.8195x over previous
//
#include <hip/hip_runtime.h>
#include <hip/hip_bf16.h>

// B=128, N=50, NB=32, K=8, H=64, D=512. sites=6400, neighbor rows=204800.
// Fused: per block, 64 neighbor rows (=2 sites) GEMM (bf16 MFMA) into LDS zbuf
// (bf16), then 3 routing iterations in-block, write fp32 out. nz never hits HBM.
// Staging: SINGLE-TYPE global_load_lds for BOTH A (raw fp32) and B (bf16),
// counted s_waitcnt vmcnt(10) + raw s_barrier — loads stay in flight across
// barriers (round-8 verified ledger). A converted fp32->bf16 at fragment read.
// This round: A LDS swizzle = full rotation (2-way conflict-free reads) and
// tail-peeled loop (no junk clamped stages).

#define D_DIM 512
#define BM 64
#define BK 32
#define KSTEPS 16

typedef __attribute__((ext_vector_type(8))) short short8;
typedef __attribute__((ext_vector_type(4))) short short4v;
typedef __attribute__((ext_vector_type(4))) float f32x4;

static __device__ __forceinline__ short f2bf(float f) {
    __bf16 b = (__bf16)f;
    return __builtin_bit_cast(short, b);
}
static __device__ __forceinline__ float bf2f(short s) {
    unsigned u = ((unsigned)(unsigned short)s) << 16;
    return __builtin_bit_cast(float, u);
}
static __device__ __forceinline__ void gload_lds16(const void* g, void* l) {
    __builtin_amdgcn_global_load_lds(
        (const __attribute__((address_space(1))) void*)g,
        (__attribute__((address_space(3))) void*)l, 16, 0, 0);
}

__global__ __launch_bounds__(256) void wconv(const float* __restrict__ W,
                                             short* __restrict__ Wb) {
    const int i = (blockIdx.x * 256 + threadIdx.x) * 8;
    const float4 v0 = *reinterpret_cast<const float4*>(W + i);
    const float4 v1 = *reinterpret_cast<const float4*>(W + i + 4);
    short8 o;
    o[0] = f2bf(v0.x); o[1] = f2bf(v0.y); o[2] = f2bf(v0.z); o[3] = f2bf(v0.w);
    o[4] = f2bf(v1.x); o[5] = f2bf(v1.y); o[6] = f2bf(v1.z); o[7] = f2bf(v1.w);
    *reinterpret_cast<short8*>(Wb + i) = o;
}

// 256 threads = 4 waves; wave w -> 64 rows x cols [128w,128w+128).
// lAf32[2]: [64][32] f32 (8 KB each) via DMA; row = 8 x 16B slots,
//   phys slot P = (G + row) & 7 (full rotation -> 2-way read, free).
// lB[2]: [512][32] bf16 (32 KB each) via DMA; row = 4 x 16B slots,
//   phys slot P = (G + (row>>1)) & 3 (conflict-free reads).
template <bool FUSED>
__global__ __launch_bounds__(256, 2) void gemm_route(
    const float* __restrict__ A,     // [R,512] fp32
    const short* __restrict__ Wb,    // [512,512] bf16
    const float* __restrict__ bias,  // [512]
    short* __restrict__ Zs,          // !FUSED: s output bf16
    const short* __restrict__ S,     // FUSED: s input bf16
    const int* __restrict__ miter_ptr,
    float* __restrict__ out)         // FUSED: [sites,512] fp32
{
    __shared__ __align__(16) char smem[81920];
    float* const lAf32 = (float*)smem;           // [2][2048] f32  (16 KB)
    short* const lB = (short*)(smem + 16384);    // [2][16384] bf16 (64 KB)

    const int t = threadIdx.x;
    const int lane = t & 63;
    const int wid = t >> 6;
    const size_t row0 = (size_t)blockIdx.x * BM;
    const int wc = wid * 128;
    const int l15 = lane & 15;

    const int cb = wc + l15;
    float bcol[8];
    #pragma unroll
    for (int n = 0; n < 8; ++n) bcol[n] = bias[cb + n * 16];
    int miter = 0;
    if (FUSED) miter = *miter_ptr;

    // 10 DMAs per wave per step: 8 B-chunks + 2 A-chunks (1024 B each).
    auto stage = [&](int step, int buf) {
        const int k0 = step * BK;
        #pragma unroll
        for (int i = 0; i < 8; ++i) {            // B: chunk = 16 rows x 64 B
            const int c = wid * 8 + i;
            const int r = c * 16 + (lane >> 2);
            const int g = ((lane & 3) - (r >> 1)) & 3;
            gload_lds16(Wb + (size_t)r * D_DIM + k0 + g * 8,
                        lB + buf * 16384 + c * 512);
        }
        #pragma unroll
        for (int i = 0; i < 2; ++i) {            // A: chunk = 8 rows x 128 B
            const int c = wid * 2 + i;
            const int r = c * 8 + (lane >> 3);
            const int g = ((lane & 7) - (lane >> 3)) & 7;   // full rotation
            gload_lds16(A + (row0 + r) * D_DIM + k0 + g * 4,
                        lAf32 + buf * 2048 + c * 256);
        }
    };

    f32x4 acc[4][8] = {};
    auto compute = [&](int buf) {
        const int sq = lane >> 4;                // k 16B-slot pair index
        short8 af[4], bfr[8];
        #pragma unroll
        for (int m = 0; m < 4; ++m) {
            const int r = m * 16 + l15;
            const float* rowp = lAf32 + buf * 2048 + r * 32;
            const int P0 = (2 * sq + r) & 7;
            const int P1 = (2 * sq + 1 + r) & 7;
            const f32x4 a0 = *reinterpret_cast<const f32x4*>(rowp + P0 * 4);
            const f32x4 a1 = *reinterpret_cast<const f32x4*>(rowp + P1 * 4);
            short8 f;
            f[0] = f2bf(a0[0]); f[1] = f2bf(a0[1]);
            f[2] = f2bf(a0[2]); f[3] = f2bf(a0[3]);
            f[4] = f2bf(a1[0]); f[5] = f2bf(a1[1]);
            f[6] = f2bf(a1[2]); f[7] = f2bf(a1[3]);
            af[m] = f;
        }
        #pragma unroll
        for (int n = 0; n < 8; ++n) {
            const int r = wc + n * 16 + l15;
            bfr[n] = *reinterpret_cast<const short8*>(
                lB + buf * 16384 + r * 32 + ((sq + (r >> 1)) & 3) * 8);
        }
        #pragma unroll
        for (int m = 0; m < 4; ++m)
            #pragma unroll
            for (int n = 0; n < 8; ++n)
                acc[m][n] = __builtin_amdgcn_mfma_f32_16x16x32_bf16(
                    af[m], bfr[n], acc[m][n], 0, 0, 0);
    };

    // ---- pipeline: counted vmcnt, single op type, loads fly across barriers
    stage(0, 0);
    stage(1, 1);
    asm volatile("s_waitcnt vmcnt(10)" ::: "memory");   // stage0 (+scalars) done
    __builtin_amdgcn_s_barrier();
    #pragma unroll
    for (int tk = 0; tk < KSTEPS - 2; ++tk) {           // tk = 0..13
        compute(tk & 1);
        asm volatile("s_waitcnt lgkmcnt(0)" ::: "memory");  // reads consumed
        __builtin_amdgcn_s_barrier();                       // buf tk&1 free
        stage(tk + 2, tk & 1);                              // overwrite it
        asm volatile("s_waitcnt vmcnt(10)" ::: "memory");   // stage(tk+1) done
        __builtin_amdgcn_s_barrier();                       // visible to all
    }
    // tk = 14: no more staging; drain stage(15) (issued at tk=13, full cover)
    compute(0);
    asm volatile("s_waitcnt lgkmcnt(0)" ::: "memory");
    __builtin_amdgcn_s_barrier();
    asm volatile("s_waitcnt vmcnt(0)" ::: "memory");        // stage(15) done
    __builtin_amdgcn_s_barrier();
    // tk = 15
    compute(1);
    asm volatile("s_waitcnt lgkmcnt(0)" ::: "memory");      // frags in regs
    __builtin_amdgcn_s_barrier();                           // lB free for zbuf

    // ---- epilogue: bias + ReLU + l2norm per 64-col group; z as bf16.
    short* const zbuf = (short*)(smem + 16384);   // aliases lB (free now)
    #pragma unroll
    for (int m = 0; m < 4; ++m) {
        #pragma unroll
        for (int r = 0; r < 4; ++r) {
            float v[8];
            float ssa = 0.0f, ssb = 0.0f;
            #pragma unroll
            for (int n = 0; n < 4; ++n) {
                v[n] = fmaxf(acc[m][n][r] + bcol[n], 0.0f);
                ssa = fmaf(v[n], v[n], ssa);
            }
            #pragma unroll
            for (int n = 4; n < 8; ++n) {
                v[n] = fmaxf(acc[m][n][r] + bcol[n], 0.0f);
                ssb = fmaf(v[n], v[n], ssb);
            }
            ssa += __shfl_xor(ssa, 1); ssb += __shfl_xor(ssb, 1);
            ssa += __shfl_xor(ssa, 2); ssb += __shfl_xor(ssb, 2);
            ssa += __shfl_xor(ssa, 4); ssb += __shfl_xor(ssb, 4);
            ssa += __shfl_xor(ssa, 8); ssb += __shfl_xor(ssb, 8);
            const float inva = 1.0f / fmaxf(sqrtf(ssa), 1e-12f);
            const float invb = 1.0f / fmaxf(sqrtf(ssb), 1e-12f);
            const int orow = m * 16 + (lane >> 4) * 4 + r;   // 0..63
            if (FUSED) {
                #pragma unroll
                for (int n = 0; n < 4; ++n)
                    zbuf[orow * D_DIM + cb + n * 16] = f2bf(v[n] * inva);
                #pragma unroll
                for (int n = 4; n < 8; ++n)
                    zbuf[orow * D_DIM + cb + n * 16] = f2bf(v[n] * invb);
            } else {
                #pragma unroll
                for (int n = 0; n < 4; ++n)
                    Zs[(row0 + orow) * D_DIM + cb + n * 16] = f2bf(v[n] * inva);
                #pragma unroll
                for (int n = 4; n < 8; ++n)
                    Zs[(row0 + orow) * D_DIM + cb + n * 16] = f2bf(v[n] * invb);
            }
        }
    }

    if (!FUSED) return;
    __syncthreads();   // zbuf complete

    // ---- routing (round-8 verified): 2 sites/block, 128 threads each.
    float* const scratch = (float*)smem;          // aliases lAf32 (free now)
    const int tt = t & 127;
    const int ssid = t >> 7;
    const size_t site = (size_t)blockIdx.x * 2 + ssid;
    float* const u_ = scratch + ssid * 512;                 // [0, 4096) bytes
    float* const p_ = (float*)(smem + 4096) + ssid * 256;   // [4096, 6144)
    const short* const zr = zbuf + ssid * 32 * D_DIM;

    const int e = tt * 4;
    const int go = tt >> 4;                  // capsule group of owned elems
    const short4v sv = *reinterpret_cast<const short4v*>(S + site * D_DIM + e);
    const float s0 = bf2f(sv[0]), s1 = bf2f(sv[1]);
    const float s2 = bf2f(sv[2]), s3 = bf2f(sv[3]);

    float v0, v1, v2, v3;
    {   // iteration 0: p uniform 1/8
        float a0 = 0, a1 = 0, a2 = 0, a3 = 0;
        for (int m = 0; m < 32; ++m) {
            const short4v z = *reinterpret_cast<const short4v*>(zr + m * D_DIM + e);
            a0 += bf2f(z[0]); a1 += bf2f(z[1]); a2 += bf2f(z[2]); a3 += bf2f(z[3]);
        }
        v0 = fmaf(a0, 0.125f, s0); v1 = fmaf(a1, 0.125f, s1);
        v2 = fmaf(a2, 0.125f, s2); v3 = fmaf(a3, 0.125f, s3);
    }

    const int dm = tt >> 2;                  // neighbor for this thread's dots
    const int ka = (tt & 3) * 2;             // capsule pair

    for (int it = 1; it < miter; ++it) {
        // normalize u per 64-group (16-thread shfl groups, wave-aligned)
        float ssum = v0 * v0 + v1 * v1 + v2 * v2 + v3 * v3;
        ssum += __shfl_xor(ssum, 1);
        ssum += __shfl_xor(ssum, 2);
        ssum += __shfl_xor(ssum, 4);
        ssum += __shfl_xor(ssum, 8);
        const float inv = 1.0f / fmaxf(sqrtf(ssum), 1e-12f);
        v0 *= inv; v1 *= inv; v2 *= inv; v3 *= inv;
        *reinterpret_cast<float4*>(u_ + e) = make_float4(v0, v1, v2, v3);
        __syncthreads();

        // dots: p[dm][ka], p[dm][ka+1]; staggered octet reads
        const short* const za = zr + dm * D_DIM + ka * 64;
        const float* const ua = u_ + ka * 64;
        float da = 0, db = 0;
        #pragma unroll
        for (int j = 0; j < 8; ++j) {
            const int jj = ((j + (tt & 7)) & 7) * 8;
            const short8 zva = *reinterpret_cast<const short8*>(za + jj);
            const short8 zvb = *reinterpret_cast<const short8*>(za + 64 + jj);
            const f32x4 uA0 = *reinterpret_cast<const f32x4*>(ua + jj);
            const f32x4 uA1 = *reinterpret_cast<const f32x4*>(ua + jj + 4);
            const f32x4 uB0 = *reinterpret_cast<const f32x4*>(ua + 64 + jj);
            const f32x4 uB1 = *reinterpret_cast<const f32x4*>(ua + 64 + jj + 4);
            #pragma unroll
            for (int qq = 0; qq < 4; ++qq) {
                da = fmaf(bf2f(zva[qq]), uA0[qq], da);
                da = fmaf(bf2f(zva[qq + 4]), uA1[qq], da);
                db = fmaf(bf2f(zvb[qq]), uB0[qq], db);
                db = fmaf(bf2f(zvb[qq + 4]), uB1[qq], db);
            }
        }
        // softmax over 8 k (4 threads x 2 vals)
        float mx = fmaxf(da, db);
        mx = fmaxf(mx, __shfl_xor(mx, 1));
        mx = fmaxf(mx, __shfl_xor(mx, 2));
        const float ea = __expf(da - mx), eb = __expf(db - mx);
        float sm_ = ea + eb;
        sm_ += __shfl_xor(sm_, 1);
        sm_ += __shfl_xor(sm_, 2);
        const float rs = 1.0f / sm_;
        *reinterpret_cast<float2*>(p_ + dm * 8 + ka) = make_float2(ea * rs, eb * rs);
        __syncthreads();

        // u = s + sum_m z[m]*p[m, go]
        float a0 = 0, a1 = 0, a2 = 0, a3 = 0;
        for (int m = 0; m < 32; ++m) {
            const short4v z = *reinterpret_cast<const short4v*>(zr + m * D_DIM + e);
            const float pm = p_[m * 8 + go];
            a0 = fmaf(bf2f(z[0]), pm, a0); a1 = fmaf(bf2f(z[1]), pm, a1);
            a2 = fmaf(bf2f(z[2]), pm, a2); a3 = fmaf(bf2f(z[3]), pm, a3);
        }
        v0 = s0 + a0; v1 = s1 + a1; v2 = s2 + a2; v3 = s3 + a3;
        // next p_ write is after next norm's barrier -> safe
    }

    *reinterpret_cast<float4*>(out + site * D_DIM + e) =
        make_float4(fmaxf(v0, 0.0f), fmaxf(v1, 0.0f),
                    fmaxf(v2, 0.0f), fmaxf(v3, 0.0f));
}

extern "C" void kernel_launch(void* const* d_in, const int* in_sizes, int n_in,
                              void* d_out, int out_size, void* d_ws, size_t ws_size,
                              hipStream_t stream) {
    const float* self_v  = (const float*)d_in[0];   // [6400,512]
    const float* neigh_v = (const float*)d_in[1];   // [204800,512]
    const float* W1      = (const float*)d_in[2];   // [512,512]
    const float* b1      = (const float*)d_in[3];   // [512]
    const int*   miter   = (const int*)d_in[4];
    float* out = (float*)d_out;

    const int sites = in_sizes[0] / D_DIM;          // 6400
    const int nrows = in_sizes[1] / D_DIM;          // 204800

    short* s  = (short*)d_ws;                       // [sites,512] bf16
    short* Wb = s + (size_t)sites * D_DIM;          // [512,512] bf16

    wconv<<<dim3(D_DIM * D_DIM / (256 * 8)), dim3(256), 0, stream>>>(W1, Wb);
    gemm_route<false><<<dim3(sites / BM), dim3(256), 0, stream>>>(
        self_v, Wb, b1, s, nullptr, nullptr, nullptr);
    gemm_route<true><<<dim3(nrows / BM), dim3(256), 0, stream>>>(
        neigh_v, Wb, b1, nullptr, s, miter, out);
}